// Round 14
// baseline (41.821 us; speedup 1.0000x reference)
//
#include <hip/hip_runtime.h>

#define NN 128
#define CCH 16
#define BB 4
#define HID 128
#define DOUT 128

typedef float v2f __attribute__((ext_vector_type(2)));

// ---------------------------------------------------------------------------
// Single fused kernel (R13 structure; only the weight supply changed).
// Block = (b, row p), 1024 threads = 16 waves, 2 blocks/CU, 8192 waves.
// XCD swizzle kept (bijective, 512 % 8 == 0).
//
// Weight supply: LDS-staged PRE-SPLATTED pairs, s_w[k][12] =
//   {wy,wy, wz,wz | ww,ww, w20,w20 | w21,w21, wx,b1}
// All lanes read the same address -> LDS broadcast, no bank conflicts, and
// each v2f constant arrives as a ready 64-bit pair: ZERO splat v_movs in the
// hot loop. Per k: 3x ds_read_b128 (broadcast) + 1 scalar fma (a-term,
// q-invariant) + 6 pk ops for the 2 cells.
// ---------------------------------------------------------------------------
__global__ __launch_bounds__(1024, 8) void fused_rey(
    const float* __restrict__ x,
    const float* __restrict__ W1, const float* __restrict__ b1,
    const float* __restrict__ W2, const float* __restrict__ b2,
    const float* __restrict__ Wc, const float* __restrict__ bc,
    float* __restrict__ y)
{
    __shared__ float s_w[HID][12];     // 6 KB pre-splatted weights
    __shared__ float s_out[CCH][NN];   // 8 KB
    __shared__ float s_diag[CCH];

    const int t    = threadIdx.x;
    const int bid0 = blockIdx.x;
    const int bid  = ((bid0 & 7) << 6) | (bid0 >> 3);   // XCD-contiguous
    const int p    = bid & 127;
    const int b    = bid >> 7;
    const int c    = t >> 6;           // 0..15, wave-uniform
    const int lane = t & 63;
    const int q0   = lane * 2;         // q pair {q0, q0+1}

    // ---- stage pre-splatted weights (threads 0..127) ----
    if (t < HID) {
        const float4 w = reinterpret_cast<const float4*>(W1)[t];
        const float w20 = W2[t], w21 = W2[HID + t];
        float* d = s_w[t];
        d[0] = w.y; d[1] = w.y; d[2]  = w.z; d[3]  = w.z;
        d[4] = w.w; d[5] = w.w; d[6]  = w20; d[7]  = w20;
        d[8] = w21; d[9] = w21; d[10] = w.x; d[11] = b1[t];
    }

    // ---- per-thread x loads (issued before the barrier; latency overlaps) --
    const size_t mbase = (size_t)(b * CCH + c) << 14;
    const float* xm = x + mbase;
    const v2f xpq = *reinterpret_cast<const v2f*>(&xm[p * NN + q0]);   // coalesced
    const v2f xqp = { xm[q0 * NN + p], xm[(q0 + 1) * NN + p] };        // strided
    const v2f xqq = { xm[q0 * (NN + 1)], xm[(q0 + 1) * (NN + 1)] };    // strided
    const float xpp = xm[p * (NN + 1)];                                // uniform

    const float bb0 = b2[0], bb1 = b2[1];
    const v2f z2 = { 0.f, 0.f };
    v2f h0 = z2, h1 = z2;

    __syncthreads();

    // ---- phase 1: hidden loop, splat-free ----
    #pragma unroll 4
    for (int k = 0; k < HID; ++k) {
        const v2f wy  = *reinterpret_cast<const v2f*>(&s_w[k][0]);
        const v2f wz  = *reinterpret_cast<const v2f*>(&s_w[k][2]);
        const v2f ww  = *reinterpret_cast<const v2f*>(&s_w[k][4]);
        const v2f w20 = *reinterpret_cast<const v2f*>(&s_w[k][6]);
        const v2f w21 = *reinterpret_cast<const v2f*>(&s_w[k][8]);
        const float wx  = s_w[k][10];
        const float b1k = s_w[k][11];
        const float a = fmaf(wx, xpp, b1k);        // q-invariant scalar
        v2f hd = __builtin_elementwise_fma(wy, xpq, (v2f){ a, a });
        hd = __builtin_elementwise_fma(wz, xqp, hd);
        hd = __builtin_elementwise_fma(ww, xqq, hd);
        hd = __builtin_elementwise_max(hd, z2);
        h0 = __builtin_elementwise_fma(w20, hd, h0);
        h1 = __builtin_elementwise_fma(w21, hd, h1);
    }

    // off-diagonal h1 (+b2[1]) -> LDS row c; (c, p) slot fixed after barrier
    const v2f o = h1 + (v2f){ bb1, bb1 };
    *reinterpret_cast<v2f*>(&s_out[c][q0]) = o;

    // diag partial: mask q==p, 64-lane wave reduce
    float s = ((q0 == p) ? 0.f : h0[0]) + ((q0 + 1 == p) ? 0.f : h0[1]);
    #pragma unroll
    for (int off = 32; off > 0; off >>= 1)
        s += __shfl_down(s, off, 64);
    if (lane == 0) s_diag[c] = s * (1.0f / (NN - 1)) + bb0;

    __syncthreads();
    if (t < CCH) s_out[t][p] = s_diag[t];
    __syncthreads();

    // ---- phase 2: y[b,d,p,:] = relu(sum_c s_out[c]*Wc[d][c] + bc[d]) ----
    const int wv = t >> 6;             // 0..15 -> 8 d's each
    const int m0 = lane * 2;
    v2f r[CCH];
    #pragma unroll
    for (int cc = 0; cc < CCH; ++cc)
        r[cc] = *reinterpret_cast<const v2f*>(&s_out[cc][m0]);

    #pragma unroll 2
    for (int dd = 0; dd < 8; ++dd) {
        const int d = wv * 8 + dd;         // wave-uniform
        const float bcv = bc[d];           // scalar load
        v2f acc = { bcv, bcv };
        #pragma unroll
        for (int cc = 0; cc < CCH; ++cc) {
            const float wcf = Wc[d * CCH + cc];   // scalar load
            acc = __builtin_elementwise_fma((v2f){ wcf, wcf }, r[cc], acc);
        }
        acc = __builtin_elementwise_max(acc, z2);
        *reinterpret_cast<v2f*>(
            &y[(((size_t)(b * DOUT + d)) * NN + p) * NN + m0]) = acc;
    }
}

extern "C" void kernel_launch(void* const* d_in, const int* in_sizes, int n_in,
                              void* d_out, int out_size, void* d_ws, size_t ws_size,
                              hipStream_t stream) {
    const float* x  = (const float*)d_in[0];
    const float* W1 = (const float*)d_in[1];
    const float* b1 = (const float*)d_in[2];
    const float* W2 = (const float*)d_in[3];
    const float* b2 = (const float*)d_in[4];
    const float* Wc = (const float*)d_in[5];
    const float* bc = (const float*)d_in[6];
    float* y = (float*)d_out;

    fused_rey<<<dim3(BB * NN), 1024, 0, stream>>>(x, W1, b1, W2, b2, Wc, bc, y);
}